// Round 2
// baseline (189.816 us; speedup 1.0000x reference)
//
#include <hip/hip_runtime.h>
#include <cmath>

// MHSA cosine-attention block, MI355X/gfx950.  Round 2.
// K1: QKV projections, lane=l, x-column in VGPRs; Q/K stored k8-tiled
//     [nh][kc=k/8][L][8] bf16 (coalesced stores, 16B frag loads); V as [nh][v][l].
// K2: flash attention, S^T = K Q^T trick -> packed ds_write_b64 P rows,
//     64 q/wave, ping-pong prefetch of K/V; numP layout [nh][ks][q][v].
// K3: coalesced reduce of numP, fp32 SIMT output projection + residual.

typedef __bf16 bf16x8 __attribute__((ext_vector_type(8)));
typedef __bf16 bf16x4 __attribute__((ext_vector_type(4)));
typedef float f4_t __attribute__((ext_vector_type(4)));

#define LQ 4096       // sequence length H*W
#define NH 4          // n*heads
#define KS 8          // key splits

__device__ inline f4_t mfma16(bf16x8 a, bf16x8 b, f4_t c) {
    return __builtin_amdgcn_mfma_f32_16x16x32_bf16(a, b, c, 0, 0, 0);
}

// ---------------------------------------------------------------------------
// Kernel 1: QKV projection + normalize.
// grid: 256 blocks = n(2) x lt(64) x gsel(2).  block: 128 thr (2 waves).
// gsel=0: waves compute Q (head=wave), V head 0 rows wave*16..+15
// gsel=1: waves compute K (head=wave), V head 1 rows wave*16..+15
// lane = l; x column (64 c) lives in VGPRs; per-thread L2 norm over dk.
// ---------------------------------------------------------------------------
__global__ __launch_bounds__(128, 1) void k1_qkv(
        const float* __restrict__ x,
        const float* __restrict__ Wq, const float* __restrict__ bq,
        const float* __restrict__ Wk, const float* __restrict__ bk,
        const float* __restrict__ Wv, const float* __restrict__ bv,
        __bf16* __restrict__ Qb, __bf16* __restrict__ Kb,
        __bf16* __restrict__ Vtb) {
    const int lane = threadIdx.x & 63;
    const int w    = threadIdx.x >> 6;       // head index for Q/K pass
    const int gsel = blockIdx.x & 1;
    const int lt   = (blockIdx.x >> 1) & 63;
    const int n    = blockIdx.x >> 7;
    const int l    = lt * 64 + lane;

    // x column -> 64 VGPRs (coalesced: lane-contiguous per c)
    float xv[64];
    const float* xp = x + (size_t)n * 64 * LQ + l;
#pragma unroll
    for (int c = 0; c < 64; ++c) xv[c] = xp[(size_t)c * LQ];

    const float* W  = gsel ? Wk : Wq;
    const float* bb = gsel ? bk : bq;
    __bf16* dst     = gsel ? Kb : Qb;
    const int nh    = n * 2 + w;

    float acc[64];
#pragma unroll 4
    for (int k = 0; k < 64; ++k) {
        const float* wr = W + (size_t)(w * 64 + k) * 64;
        float a = bb[w * 64 + k];
#pragma unroll
        for (int c4 = 0; c4 < 16; ++c4) {
            f4_t t = *(const f4_t*)(wr + c4 * 4);   // broadcast (uniform addr)
            a = fmaf(t[0], xv[c4 * 4 + 0], a);
            a = fmaf(t[1], xv[c4 * 4 + 1], a);
            a = fmaf(t[2], xv[c4 * 4 + 2], a);
            a = fmaf(t[3], xv[c4 * 4 + 3], a);
        }
        acc[k] = a;
    }

    // per-thread L2 norm over the full dk=64 vector
    float ss = 0.f;
#pragma unroll
    for (int k = 0; k < 64; ++k) ss = fmaf(acc[k], acc[k], ss);
    const float rn = 1.0f / fmaxf(sqrtf(ss), 1e-6f);

    // k8-tiled store: dst[(nh*8 + kc)*LQ + l)*8 + j]  -- lane-contiguous 16B
#pragma unroll
    for (int kc = 0; kc < 8; ++kc) {
        bf16x8 v8;
#pragma unroll
        for (int j = 0; j < 8; ++j) v8[j] = (__bf16)(acc[kc * 8 + j] * rn);
        *(bf16x8*)(dst + ((size_t)(nh * 8 + kc) * LQ + l) * 8) = v8;
    }

    // V pass: head hv = gsel, rows w*16 .. w*16+15 (no norm)
    const int hv = gsel;
#pragma unroll 2
    for (int vr = 0; vr < 16; ++vr) {
        const int row = hv * 32 + w * 16 + vr;     // h*32+v
        const float* wr = Wv + (size_t)row * 64;
        float a = bv[row];
#pragma unroll
        for (int c4 = 0; c4 < 16; ++c4) {
            f4_t t = *(const f4_t*)(wr + c4 * 4);
            a = fmaf(t[0], xv[c4 * 4 + 0], a);
            a = fmaf(t[1], xv[c4 * 4 + 1], a);
            a = fmaf(t[2], xv[c4 * 4 + 2], a);
            a = fmaf(t[3], xv[c4 * 4 + 3], a);
        }
        Vtb[(size_t)((n * 2 + hv) * 32 + row - hv * 32 * 0) * LQ + l] = (__bf16)a;
    }
}

// ---------------------------------------------------------------------------
// Kernel 2: flash attention (scores in [-1,1], no max tracking).
// grid: (16 q-blocks of 256, nh=4, ks=8) = 512 blocks.  block: 256 thr.
// wave owns 64 q; 16 chunks of 32 keys, ping-pong K/V prefetch.
// S^T = K Q^T  =>  C lane holds 4 consecutive KEYS for one q  =>  P row
// writes pack to ds_write_b64; PV B-frag read is ds_read_b128.
// ---------------------------------------------------------------------------
__global__ __launch_bounds__(256, 2) void k2_attn(
        const __bf16* __restrict__ Qb, const __bf16* __restrict__ Kb,
        const __bf16* __restrict__ Vtb,
        float* __restrict__ numP, float* __restrict__ denP) {
    const int lane = threadIdx.x & 63;
    const int wave = threadIdx.x >> 6;
    const int quad = lane >> 4;
    const int l15  = lane & 15;
    const int nh   = blockIdx.y;
    const int ks   = blockIdx.z;
    const int qbase = blockIdx.x * 256 + wave * 64;
    const int kbase = ks * 512;

    __shared__ __bf16 P[4][4][16][40];   // [wave][qt][q-row][32 keys + pad]

    const f4_t fzero = {0.f, 0.f, 0.f, 0.f};

    // Q fragments (k8-tiled layout), reused for all 512 keys
    bf16x8 qf[4][2];
#pragma unroll
    for (int qt = 0; qt < 4; ++qt)
#pragma unroll
        for (int kh = 0; kh < 2; ++kh)
            qf[qt][kh] = *(const bf16x8*)(Qb +
                ((size_t)(nh * 8 + kh * 4 + quad) * LQ + qbase + qt * 16 + l15) * 8);

    f4_t racc[2][4];                     // [vt][qt]: (v=vt*16+quad*4+r, q=qt*16+l15)
#pragma unroll
    for (int a = 0; a < 2; ++a)
#pragma unroll
        for (int b = 0; b < 4; ++b) racc[a][b] = fzero;
    float den[4] = {0.f, 0.f, 0.f, 0.f};

    // ping-pong K/V fragment buffers
    bf16x8 kfb[2][2][2], vfb[2][2];
#pragma unroll
    for (int kt = 0; kt < 2; ++kt)
#pragma unroll
        for (int kh = 0; kh < 2; ++kh)
            kfb[0][kt][kh] = *(const bf16x8*)(Kb +
                ((size_t)(nh * 8 + kh * 4 + quad) * LQ + kbase + kt * 16 + l15) * 8);
#pragma unroll
    for (int vt = 0; vt < 2; ++vt)
        vfb[0][vt] = *(const bf16x8*)(Vtb +
            (size_t)(nh * 32 + vt * 16 + l15) * LQ + kbase + quad * 8);

#pragma unroll 2
    for (int ch = 0; ch < 16; ++ch) {
        const int cur = ch & 1, nxt = cur ^ 1;
        const int kb2 = kbase + (ch < 15 ? ch + 1 : 15) * 32;   // prefetch target

        // prefetch next chunk's K/V fragments (overlaps this chunk's compute)
#pragma unroll
        for (int kt = 0; kt < 2; ++kt)
#pragma unroll
            for (int kh = 0; kh < 2; ++kh)
                kfb[nxt][kt][kh] = *(const bf16x8*)(Kb +
                    ((size_t)(nh * 8 + kh * 4 + quad) * LQ + kb2 + kt * 16 + l15) * 8);
#pragma unroll
        for (int vt = 0; vt < 2; ++vt)
            vfb[nxt][vt] = *(const bf16x8*)(Vtb +
                (size_t)(nh * 32 + vt * 16 + l15) * LQ + kb2 + quad * 8);

#pragma unroll
        for (int qt = 0; qt < 4; ++qt) {
#pragma unroll
            for (int kt = 0; kt < 2; ++kt) {
                // S^T tile: m=key (quad*4+r), n=q (l15)
                f4_t s = mfma16(kfb[cur][kt][0], qf[qt][0], fzero);
                s      = mfma16(kfb[cur][kt][1], qf[qt][1], s);
                bf16x4 pv;
                float d = 0.f;
#pragma unroll
                for (int r = 0; r < 4; ++r) {
                    float p = __expf(s[r]);
                    d += p;
                    pv[r] = (__bf16)p;
                }
                den[qt] += d;
                *(bf16x4*)&P[wave][qt][l15][kt * 16 + quad * 4] = pv;  // b64, packed
            }
            // PV: A = V^T rows (key-major), B = P rows (key-major)
            bf16x8 pf = *(const bf16x8*)&P[wave][qt][l15][quad * 8];   // b128
#pragma unroll
            for (int vt = 0; vt < 2; ++vt)
                racc[vt][qt] = mfma16(vfb[cur][vt], pf, racc[vt][qt]);
        }
    }

    // den: reduce the 4 quad-partials (same q = l15 across quads)
#pragma unroll
    for (int qt = 0; qt < 4; ++qt) {
        den[qt] += __shfl_xor(den[qt], 16, 64);
        den[qt] += __shfl_xor(den[qt], 32, 64);
    }

    const size_t pb = (size_t)(nh * KS + ks) * LQ;
    // numP layout [nh][ks][q][v32] -- v-contiguous for k3's coalesced reads
#pragma unroll
    for (int vt = 0; vt < 2; ++vt)
#pragma unroll
        for (int qt = 0; qt < 4; ++qt)
#pragma unroll
            for (int r = 0; r < 4; ++r)
                numP[(pb + qbase + qt * 16 + l15) * 32 + vt * 16 + quad * 4 + r]
                    = racc[vt][qt][r];

    if (lane < 16)
#pragma unroll
        for (int qt = 0; qt < 4; ++qt)
            denP[pb + qbase + qt * 16 + lane] = den[qt];
}

// ---------------------------------------------------------------------------
// Kernel 3: reduce partials -> R, fp32 SIMT output projection + residual.
// grid: 128 blocks = n(2) x 64 l-tiles of 64.  block: 256 thr = 4 waves.
// numP reads are v-contiguous (coalesced); Rf in LDS fp32.
// ---------------------------------------------------------------------------
__global__ __launch_bounds__(256) void k3_out(
        const float* __restrict__ numP, const float* __restrict__ denP,
        const float* __restrict__ Wm, const float* __restrict__ bm,
        const float* __restrict__ x, float* __restrict__ out) {
    const int tid  = threadIdx.x;
    const int lane = tid & 63;
    const int wv   = tid >> 6;
    const int n    = blockIdx.x >> 6;
    const int lt   = blockIdx.x & 63;
    const int l0   = lt * 64;

    __shared__ float Rf[64][65];    // [j = h*32+v][l], +1 pad
    __shared__ float dinv[2][64];

    // denominator reciprocals
    if (tid < 128) {
        const int hh = tid >> 6, li = tid & 63;
        float s = 0.f;
#pragma unroll
        for (int k = 0; k < KS; ++k)
            s += denP[(size_t)((n * 2 + hh) * KS + k) * LQ + l0 + li];
        dinv[hh][li] = 1.0f / s;
    }

    // reduce numP over ks: thread (v = tid&31, lsub = tid>>5) owns 2hh x 8l
    {
        const int v = tid & 31, lsub = tid >> 5;
#pragma unroll
        for (int hh = 0; hh < 2; ++hh) {
            const size_t base = (size_t)(n * 2 + hh) * KS * LQ;
#pragma unroll
            for (int i = 0; i < 8; ++i) {
                const int l = lsub + 8 * i;
                float s = 0.f;
#pragma unroll
                for (int k = 0; k < KS; ++k)
                    s += numP[(base + (size_t)k * LQ + l0 + l) * 32 + v];
                Rf[hh * 32 + v][l] = s;
            }
        }
    }
    __syncthreads();

    // projection: wave wv -> outputs o = wv*16..+15, lane = l
    const float d0 = dinv[0][lane], d1 = dinv[1][lane];
    float rj[64];
#pragma unroll
    for (int j = 0; j < 64; ++j)
        rj[j] = Rf[j][lane] * (j < 32 ? d0 : d1);

    float acc[16];
#pragma unroll
    for (int oi = 0; oi < 16; ++oi) acc[oi] = bm[wv * 16 + oi];
#pragma unroll 2
    for (int oi = 0; oi < 16; ++oi) {
        const float* wr = Wm + (size_t)(wv * 16 + oi) * 64;
        float a = acc[oi];
#pragma unroll
        for (int j4 = 0; j4 < 16; ++j4) {
            f4_t t = *(const f4_t*)(wr + j4 * 4);   // broadcast
            a = fmaf(t[0], rj[j4 * 4 + 0], a);
            a = fmaf(t[1], rj[j4 * 4 + 1], a);
            a = fmaf(t[2], rj[j4 * 4 + 2], a);
            a = fmaf(t[3], rj[j4 * 4 + 3], a);
        }
        acc[oi] = a;
    }

    // epilogue: + residual, coalesced fp32
#pragma unroll
    for (int oi = 0; oi < 16; ++oi) {
        const int o = wv * 16 + oi;
        const size_t idx = (size_t)(n * 64 + o) * LQ + l0 + lane;
        out[idx] = acc[oi] + x[idx];
    }
}

// ---------------------------------------------------------------------------
extern "C" void kernel_launch(void* const* d_in, const int* in_sizes, int n_in,
                              void* d_out, int out_size, void* d_ws, size_t ws_size,
                              hipStream_t stream) {
    const float* x  = (const float*)d_in[0];
    const float* Wq = (const float*)d_in[1];
    const float* bq = (const float*)d_in[2];
    const float* Wk = (const float*)d_in[3];
    const float* bk = (const float*)d_in[4];
    const float* Wv = (const float*)d_in[5];
    const float* bv = (const float*)d_in[6];
    const float* Wm = (const float*)d_in[7];
    const float* bm = (const float*)d_in[8];
    float* out = (float*)d_out;

    // workspace carve: Qb 2MB | Kb 2MB | Vtb 1MB | numP 16.8MB | denP 0.5MB
    __bf16* Qb  = (__bf16*)d_ws;
    __bf16* Kb  = Qb + (size_t)NH * LQ * 64;
    __bf16* Vtb = Kb + (size_t)NH * LQ * 64;
    float*  numP = (float*)(Vtb + (size_t)NH * 32 * LQ);
    float*  denP = numP + (size_t)NH * KS * 32 * LQ;

    k1_qkv<<<dim3(256), dim3(128), 0, stream>>>(x, Wq, bq, Wk, bk, Wv, bv,
                                                Qb, Kb, Vtb);
    k2_attn<<<dim3(16, NH, KS), dim3(256), 0, stream>>>(Qb, Kb, Vtb, numP, denP);
    k3_out<<<dim3(128), dim3(256), 0, stream>>>(numP, denP, Wm, bm, x, out);
}